// Round 4
// baseline (783.445 us; speedup 1.0000x reference)
//
#include <hip/hip_runtime.h>
#include <hip/hip_bf16.h>

// MoE: B=4,S=4096,D=512,E=16,H=2048,top-2. T=16384 tokens, 32768 slots.
#define T_TOK 16384
#define DDIM  512
#define NEXP  16
#define HDIM  2048
#define NSLOT (T_TOK * 2)

#define GBM 128           // gemm tile M
#define GBN 128           // gemm tile N
#define MAXTILE 272       // max m-tiles: 32768/128 + 16

typedef __attribute__((ext_vector_type(8))) short short8;   // 8 x bf16
typedef __attribute__((ext_vector_type(4))) short short4v;
typedef __attribute__((ext_vector_type(4))) float f32x4;

__device__ inline short f2bf(float f) {
    __hip_bfloat16 h = __float2bfloat16(f);
    return *reinterpret_cast<short*>(&h);
}
__device__ inline float geluf(float v) {   // exact gelu
    return 0.5f * v * (1.0f + erff(v * 0.70710678118654752440f));
}
// async global->LDS, 16B per lane. LDS dest = uniform base + lane*16.
__device__ inline void gload16(const void* g, void* l) {
    __builtin_amdgcn_global_load_lds(
        (const __attribute__((address_space(1))) void*)g,
        (__attribute__((address_space(3))) void*)l, 16, 0, 0);
}

// ---------------- routing ----------------
// wave-per-token gate: lane (g,q) = (d-quarter, expert). fp64 throughout
// (tie-robust vs np ref). No LDS, no atomics.
__global__ __launch_bounds__(256) void gate_kernel(
    const float* __restrict__ x, const float* __restrict__ wg,
    const float* __restrict__ bg, int* __restrict__ tok_e,
    float* __restrict__ tok_w)
{
    int wv = threadIdx.x >> 6, lane = threadIdx.x & 63;
    int t = blockIdx.x * 4 + wv;
    int g = lane >> 4, q = lane & 15;
    const float* xr = x + (size_t)t * DDIM + g * 128;
    const float* wr = wg + (size_t)g * 128 * NEXP + q;
    double a0 = 0, a1 = 0, a2 = 0, a3 = 0;
#pragma unroll
    for (int c = 0; c < 8; ++c) {
        float4 v0 = ((const float4*)xr)[c * 4 + 0];
        float4 v1 = ((const float4*)xr)[c * 4 + 1];
        float4 v2 = ((const float4*)xr)[c * 4 + 2];
        float4 v3 = ((const float4*)xr)[c * 4 + 3];
        const float* wp = wr + c * 16 * NEXP;
        a0 += (double)v0.x * (double)wp[0 * NEXP];
        a1 += (double)v0.y * (double)wp[1 * NEXP];
        a2 += (double)v0.z * (double)wp[2 * NEXP];
        a3 += (double)v0.w * (double)wp[3 * NEXP];
        a0 += (double)v1.x * (double)wp[4 * NEXP];
        a1 += (double)v1.y * (double)wp[5 * NEXP];
        a2 += (double)v1.z * (double)wp[6 * NEXP];
        a3 += (double)v1.w * (double)wp[7 * NEXP];
        a0 += (double)v2.x * (double)wp[8 * NEXP];
        a1 += (double)v2.y * (double)wp[9 * NEXP];
        a2 += (double)v2.z * (double)wp[10 * NEXP];
        a3 += (double)v2.w * (double)wp[11 * NEXP];
        a0 += (double)v3.x * (double)wp[12 * NEXP];
        a1 += (double)v3.y * (double)wp[13 * NEXP];
        a2 += (double)v3.z * (double)wp[14 * NEXP];
        a3 += (double)v3.w * (double)wp[15 * NEXP];
    }
    double a = ((a0 + a1) + (a2 + a3));
    a += __shfl_xor(a, 16, 64);
    a += __shfl_xor(a, 32, 64);
    a += (double)bg[q];
    // butterfly argmax over the 16 lanes of each quarter-group (all agree)
    double v0 = a; int i0 = q;
#pragma unroll
    for (int s = 1; s < 16; s <<= 1) {
        double ov = __shfl_xor(v0, s, 64);
        int oi = __shfl_xor(i0, s, 64);
        if (ov > v0 || (ov == v0 && oi < i0)) { v0 = ov; i0 = oi; }
    }
    double m2 = (q == i0) ? -1e300 : a;
    double v1 = m2; int i1 = q;
#pragma unroll
    for (int s = 1; s < 16; s <<= 1) {
        double ov = __shfl_xor(v1, s, 64);
        int oi = __shfl_xor(i1, s, 64);
        if (ov > v1 || (ov == v1 && oi < i1)) { v1 = ov; i1 = oi; }
    }
    if (lane == 0) {
        float ex = expf((float)(v1 - v0));      // <= 1
        float w0 = 1.0f / (1.0f + ex);
        tok_e[2 * t] = i0; tok_e[2 * t + 1] = i1;
        tok_w[2 * t] = w0; tok_w[2 * t + 1] = ex * w0;
    }
}

__global__ __launch_bounds__(256) void count_kernel(
    const int* __restrict__ tok_e, int* __restrict__ counts)
{
    __shared__ int h[NEXP];
    if (threadIdx.x < NEXP) h[threadIdx.x] = 0;
    __syncthreads();
    for (int i = blockIdx.x * 256 + threadIdx.x; i < NSLOT; i += 32 * 256)
        atomicAdd(&h[tok_e[i]], 1);
    __syncthreads();
    if (threadIdx.x < NEXP && h[threadIdx.x])
        atomicAdd(&counts[threadIdx.x], h[threadIdx.x]);
}

// offs[0..16] = exclusive scan; offs[17] = ntiles; builds compact tile table
__global__ void scan_kernel(const int* __restrict__ counts, int* __restrict__ offs,
                            int* __restrict__ cursors, int* __restrict__ tile_e,
                            int* __restrict__ tile_m0)
{
    if (threadIdx.x == 0) {
        int run = 0;
        for (int e = 0; e < NEXP; ++e) { offs[e] = run; cursors[e] = run; run += counts[e]; }
        offs[NEXP] = run;
        int nt = 0;
        for (int e = 0; e < NEXP; ++e)
            for (int m = offs[e]; m < offs[e + 1]; m += GBM) {
                tile_e[nt] = e; tile_m0[nt] = m; ++nt;
            }
        offs[17] = nt;
    }
}

// per-wave ballot aggregation: ~16 atomics/wave instead of 64
__global__ __launch_bounds__(256) void scatter_kernel(
    const int* __restrict__ tok_e, const float* __restrict__ tok_w,
    int* __restrict__ cursors, int* __restrict__ list_tok,
    float* __restrict__ list_w, int* __restrict__ pos_tk)
{
    int s = blockIdx.x * 256 + threadIdx.x;   // slot id
    int lane = threadIdx.x & 63;
    int e = tok_e[s];
    float w = tok_w[s];
    int pos = 0;
#pragma unroll 1
    for (int ex = 0; ex < NEXP; ++ex) {
        unsigned long long m = __ballot(e == ex);
        if (m == 0) continue;
        if (e == ex) {
            int rank = __popcll(m & ((1ull << lane) - 1ull));
            int leader = __ffsll((long long)m) - 1;
            int base = 0;
            if (lane == leader) base = atomicAdd(&cursors[ex], (int)__popcll(m));
            base = __shfl(base, leader, 64);
            pos = base + rank;
        }
    }
    list_tok[pos] = s >> 1;
    list_w[pos] = w;
    pos_tk[s] = pos;
}

// ---------------- pre-conversion ----------------

__global__ void cvt_bf16_kernel(const float* __restrict__ src, short* __restrict__ dst, int n4)
{
    int i = blockIdx.x * blockDim.x + threadIdx.x;
    int stride = gridDim.x * blockDim.x;
    for (; i < n4; i += stride) {
        float4 v = ((const float4*)src)[i];
        short4v o;
        o[0] = f2bf(v.x); o[1] = f2bf(v.y); o[2] = f2bf(v.z); o[3] = f2bf(v.w);
        ((short4v*)dst)[i] = o;
    }
}

// transpose one [R][C] fp32 matrix per blockIdx.z into [C][R] bf16
__global__ void wtrans_kernel(const float* __restrict__ src, short* __restrict__ dst, int R, int C)
{
    __shared__ float t[32][33];
    int c0 = blockIdx.x * 32, r0 = blockIdx.y * 32;
    const float* s = src + (size_t)blockIdx.z * R * C;
    short* d = dst + (size_t)blockIdx.z * R * C;
    int cc = threadIdx.x & 31, rr = threadIdx.x >> 5;
#pragma unroll
    for (int pp = 0; pp < 4; ++pp)
        t[rr + pp * 8][cc] = s[(size_t)(r0 + rr + pp * 8) * C + c0 + cc];
    __syncthreads();
#pragma unroll
    for (int pp = 0; pp < 4; ++pp) {
        int c = rr + pp * 8;
        d[(size_t)(c0 + c) * R + r0 + cc] = f2bf(t[cc][c]);
    }
}

// ---------------- expert GEMMs (m97 structure, single-buffer: 4 blk/CU) -------
// 128x128 tile, BK=64, 256 threads = 4 waves (2m x 2n), 64x64 per wave,
// linear LDS, global_load_lds width-16 staging, 2 barriers/K.
// NOTE round-3 lesson: explicit dbuf doubled LDS -> occupancy 4->2 blk/CU,
// regressed 28us (matches guide m99/m132). Keep single-buffer.

__global__ __launch_bounds__(256) void gemm1_kernel(
    const short* __restrict__ xbf, const short* __restrict__ w1t,
    const float* __restrict__ b1, const int* __restrict__ offs,
    const int* __restrict__ tile_e, const int* __restrict__ tile_m0,
    const int* __restrict__ list_tok, short* __restrict__ hbuf,
    int h0, int hlen)
{
    if ((int)blockIdx.x >= offs[17]) return;
    int e = tile_e[blockIdx.x], m0 = tile_m0[blockIdx.x];
    int rows = offs[e + 1] - m0; if (rows > GBM) rows = GBM;
    int n0 = blockIdx.y * GBN;            // chunk-relative h
    int tid = threadIdx.x, lane = tid & 63, w = tid >> 6;

    __shared__ __align__(16) short As[GBM * 64];
    __shared__ __align__(16) short Bs[GBN * 64];
    __shared__ int ts[GBM];
    if (tid < GBM) ts[tid] = list_tok[m0 + (tid < rows ? tid : rows - 1)];
    __syncthreads();

    // staging: wave w owns LDS rows [w*32, w*32+32); instr i stages 8 rows.
    int srow = w * 32 + (lane >> 3);
    int seg = (lane & 7) * 8;             // k-element offset of this lane's 16B
    const short* ga[4]; const short* gb[4];
#pragma unroll
    for (int i = 0; i < 4; ++i)
        ga[i] = xbf + (size_t)ts[srow + i * 8] * DDIM + seg;
    const short* brow = w1t + ((size_t)e * HDIM + (size_t)(h0 + n0) + srow) * DDIM + seg;
#pragma unroll
    for (int i = 0; i < 4; ++i)
        gb[i] = brow + (size_t)(i * 8) * DDIM;
    short* lA = As + w * 2048;
    short* lB = Bs + w * 2048;

    int wm = w >> 1, wn = w & 1;
    int a_r = wm * 64 + (lane & 15);
    int b_r = wn * 64 + (lane & 15);
    int kf = (lane >> 4) * 8;

    f32x4 vzero = {0.0f, 0.0f, 0.0f, 0.0f};
    f32x4 acc[4][4];
#pragma unroll
    for (int i = 0; i < 4; ++i)
#pragma unroll
        for (int j = 0; j < 4; ++j) acc[i][j] = vzero;

#pragma unroll 1
    for (int kb = 0; kb < DDIM / 64; ++kb) {
#pragma unroll
        for (int i = 0; i < 4; ++i) gload16(ga[i] + kb * 64, lA + i * 512);
#pragma unroll
        for (int i = 0; i < 4; ++i) gload16(gb[i] + kb * 64, lB + i * 512);
        __syncthreads();
#pragma unroll
        for (int ks = 0; ks < 2; ++ks) {
            short8 af[4], bfv[4];
            int ko = ks * 32 + kf;
#pragma unroll
            for (int mi = 0; mi < 4; ++mi)
                af[mi] = *(const short8*)(As + (a_r + mi * 16) * 64 + ko);
#pragma unroll
            for (int ni = 0; ni < 4; ++ni)
                bfv[ni] = *(const short8*)(Bs + (b_r + ni * 16) * 64 + ko);
#pragma unroll
            for (int mi = 0; mi < 4; ++mi)
#pragma unroll
                for (int ni = 0; ni < 4; ++ni)
                    acc[mi][ni] = __builtin_amdgcn_mfma_f32_16x16x32_bf16(
                        af[mi], bfv[ni], acc[mi][ni], 0, 0, 0);
        }
        __syncthreads();
    }

    int crow = wm * 64 + ((lane >> 4) << 2);
    int ccol = wn * 64 + (lane & 15);
#pragma unroll
    for (int mi = 0; mi < 4; ++mi) {
#pragma unroll
        for (int ni = 0; ni < 4; ++ni) {
            int col = ccol + ni * 16;
            float bias = b1[e * HDIM + h0 + n0 + col];
#pragma unroll
            for (int j = 0; j < 4; ++j) {
                int row = crow + mi * 16 + j;
                if (row < rows) {
                    float v = acc[mi][ni][j] + bias;
                    hbuf[(size_t)(m0 + row) * hlen + (n0 + col)] = f2bf(geluf(v));
                }
            }
        }
    }
}

__global__ __launch_bounds__(256) void gemm2_kernel(
    const short* __restrict__ hbuf, const short* __restrict__ w2t,
    const float* __restrict__ b2, const int* __restrict__ offs,
    const int* __restrict__ tile_e, const int* __restrict__ tile_m0,
    const int* __restrict__ list_tok, const float* __restrict__ list_w,
    float* __restrict__ ybuf, float* __restrict__ out,
    int h0, int hlen, int mode)
{
    if ((int)blockIdx.x >= offs[17]) return;
    int e = tile_e[blockIdx.x], m0 = tile_m0[blockIdx.x];
    int rows = offs[e + 1] - m0; if (rows > GBM) rows = GBM;
    int n0 = blockIdx.y * GBN;            // output d coordinate
    int tid = threadIdx.x, lane = tid & 63, w = tid >> 6;

    __shared__ __align__(16) short As[GBM * 64];
    __shared__ __align__(16) short Bs[GBN * 64];
    __shared__ int ts[GBM];
    __shared__ float lw[GBM];
    if (tid < GBM) {
        int idx = m0 + (tid < rows ? tid : rows - 1);
        ts[tid] = list_tok[idx];
        lw[tid] = list_w[idx];
    }
    __syncthreads();

    int srow = w * 32 + (lane >> 3);
    int seg = (lane & 7) * 8;
    const short* ga[4]; const short* gb[4];
#pragma unroll
    for (int i = 0; i < 4; ++i) {
        int slot = m0 + srow + i * 8; if (slot >= NSLOT) slot = NSLOT - 1;
        ga[i] = hbuf + (size_t)slot * hlen + seg;
    }
    const short* brow = w2t + ((size_t)e * DDIM + n0 + srow) * HDIM + h0 + seg;
#pragma unroll
    for (int i = 0; i < 4; ++i)
        gb[i] = brow + (size_t)(i * 8) * HDIM;
    short* lA = As + w * 2048;
    short* lB = Bs + w * 2048;

    int wm = w >> 1, wn = w & 1;
    int a_r = wm * 64 + (lane & 15);
    int b_r = wn * 64 + (lane & 15);
    int kf = (lane >> 4) * 8;

    f32x4 vzero = {0.0f, 0.0f, 0.0f, 0.0f};
    f32x4 acc[4][4];
#pragma unroll
    for (int i = 0; i < 4; ++i)
#pragma unroll
        for (int j = 0; j < 4; ++j) acc[i][j] = vzero;

    int nkb = hlen >> 6;
#pragma unroll 1
    for (int kb = 0; kb < nkb; ++kb) {
#pragma unroll
        for (int i = 0; i < 4; ++i) gload16(ga[i] + kb * 64, lA + i * 512);
#pragma unroll
        for (int i = 0; i < 4; ++i) gload16(gb[i] + kb * 64, lB + i * 512);
        __syncthreads();
#pragma unroll
        for (int ks = 0; ks < 2; ++ks) {
            short8 af[4], bfv[4];
            int ko = ks * 32 + kf;
#pragma unroll
            for (int mi = 0; mi < 4; ++mi)
                af[mi] = *(const short8*)(As + (a_r + mi * 16) * 64 + ko);
#pragma unroll
            for (int ni = 0; ni < 4; ++ni)
                bfv[ni] = *(const short8*)(Bs + (b_r + ni * 16) * 64 + ko);
#pragma unroll
            for (int mi = 0; mi < 4; ++mi)
#pragma unroll
                for (int ni = 0; ni < 4; ++ni)
                    acc[mi][ni] = __builtin_amdgcn_mfma_f32_16x16x32_bf16(
                        af[mi], bfv[ni], acc[mi][ni], 0, 0, 0);
        }
        __syncthreads();
    }

    int crow = wm * 64 + ((lane >> 4) << 2);
    int ccol = wn * 64 + (lane & 15);
#pragma unroll
    for (int mi = 0; mi < 4; ++mi) {
#pragma unroll
        for (int ni = 0; ni < 4; ++ni) {
            int col = ccol + ni * 16;
            float bias = (h0 == 0) ? b2[e * DDIM + n0 + col] : 0.0f;
#pragma unroll
            for (int j = 0; j < 4; ++j) {
                int row = crow + mi * 16 + j;
                if (row < rows) {
                    float v = acc[mi][ni][j] + bias;
                    if (mode == 0) {
                        float* yp = ybuf + (size_t)(m0 + row) * DDIM + n0 + col;
                        *yp = (h0 == 0) ? v : (*yp + v);
                    } else {
                        atomicAdd(&out[(size_t)ts[row] * DDIM + n0 + col], lw[row] * v);
                    }
                }
            }
        }
    }
}

// out[t] = w0*ybuf[pos0] + w1*ybuf[pos1]
__global__ __launch_bounds__(256) void combine_kernel(
    const float* __restrict__ ybuf, const int* __restrict__ pos_tk,
    const float* __restrict__ tok_w, float* __restrict__ out)
{
    int i = blockIdx.x * 256 + threadIdx.x;   // over T_TOK * 128 float4 units
    int t = i >> 7, c = i & 127;
    float w0 = tok_w[2 * t], w1 = tok_w[2 * t + 1];
    int p0 = pos_tk[2 * t], p1 = pos_tk[2 * t + 1];
    float4 a = ((const float4*)ybuf)[(size_t)p0 * 128 + c];
    float4 b = ((const float4*)ybuf)[(size_t)p1 * 128 + c];
    float4 o;
    o.x = w0 * a.x + w1 * b.x;
    o.y = w0 * a.y + w1 * b.y;
    o.z = w0 * a.z + w1 * b.z;
    o.w = w0 * a.w + w1 * b.w;
    ((float4*)out)[(size_t)t * 128 + c] = o;
}

// ---------------- launch ----------------

extern "C" void kernel_launch(void* const* d_in, const int* in_sizes, int n_in,
                              void* d_out, int out_size, void* d_ws, size_t ws_size,
                              hipStream_t stream)
{
    const float* x  = (const float*)d_in[0];
    const float* wg = (const float*)d_in[1];
    const float* bg = (const float*)d_in[2];
    const float* w1 = (const float*)d_in[3];
    const float* b1 = (const float*)d_in[4];
    const float* w2 = (const float*)d_in[5];
    const float* b2 = (const float*)d_in[6];
    float* out = (float*)d_out;

    char* p = (char*)d_ws;
    int* counts   = (int*)(p);                  // 64 B
    int* cursors  = (int*)(p + 64);             // 64 B
    int* offs     = (int*)(p + 128);            // 32 ints
    int* tile_e   = (int*)(p + 256);            // 512 ints
    int* tile_m0  = (int*)(p + 2304);           // 512 ints
    int* tok_e    = (int*)(p + 8192);           // 128 KiB
    float* tok_w  = (float*)(p + 8192 + 131072);
    int* list_tok = (int*)(p + 8192 + 262144);
    float* list_w = (float*)(p + 8192 + 393216);
    int* pos_tk   = (int*)(p + 8192 + 524288);
    short* xbf    = (short*)(p + 8192 + 655360);              // 16 MiB
    short* w1t    = xbf + (size_t)T_TOK * DDIM;               // 32 MiB
    short* w2t    = w1t + (size_t)NEXP * DDIM * HDIM;         // 32 MiB
    char* after   = (char*)(w2t + (size_t)NEXP * DDIM * HDIM);
    size_t fixed  = (size_t)(after - p);

    // hlen preference: 512 first — keeps the per-chunk hbuf (33 MB) L3/L2-hot
    // between the gemm1 chunk that writes it and the gemm2 chunk that reads it
    // (round-2 FETCH showed hlen=2048's 134 MB hbuf misses L3 entirely).
    static const int pref[5] = {512, 1024, 2048, 256, 128};
    int hlen = 0, mode = 0;
    for (int i = 0; i < 5; ++i) {
        int hl = pref[i];
        if (fixed + (size_t)NSLOT * DDIM * 4 + (size_t)NSLOT * hl * 2 <= ws_size) { hlen = hl; mode = 0; break; }
    }
    if (!hlen)
        for (int i = 0; i < 5; ++i) {
            int hl = pref[i];
            if (fixed + (size_t)NSLOT * hl * 2 <= ws_size) { hlen = hl; mode = 1; break; }
        }

    float* ybuf = (float*)after;
    short* hbuf = (mode == 0) ? (short*)(after + (size_t)NSLOT * DDIM * 4) : (short*)after;

    if (!hlen) { hipMemsetAsync(d_out, 0, (size_t)out_size * sizeof(float), stream); return; }
    if (mode == 1) hipMemsetAsync(d_out, 0, (size_t)out_size * sizeof(float), stream);
    hipMemsetAsync(counts, 0, 64, stream);

    gate_kernel<<<T_TOK / 4, 256, 0, stream>>>(x, wg, bg, tok_e, tok_w);
    count_kernel<<<32, 256, 0, stream>>>(tok_e, counts);
    scan_kernel<<<1, 64, 0, stream>>>(counts, offs, cursors, tile_e, tile_m0);
    scatter_kernel<<<NSLOT / 256, 256, 0, stream>>>(tok_e, tok_w, cursors, list_tok, list_w, pos_tk);
    cvt_bf16_kernel<<<2048, 256, 0, stream>>>(x, xbf, T_TOK * DDIM / 4);
    wtrans_kernel<<<dim3(HDIM / 32, DDIM / 32, NEXP), 256, 0, stream>>>(w1, w1t, DDIM, HDIM);
    wtrans_kernel<<<dim3(DDIM / 32, HDIM / 32, NEXP), 256, 0, stream>>>(w2, w2t, HDIM, DDIM);

    for (int h0 = 0; h0 < HDIM; h0 += hlen) {
        gemm1_kernel<<<dim3(MAXTILE, hlen / GBN), 256, 0, stream>>>(
            xbf, w1t, b1, offs, tile_e, tile_m0, list_tok, hbuf, h0, hlen);
        gemm2_kernel<<<dim3(MAXTILE, DDIM / GBN), 256, 0, stream>>>(
            hbuf, w2t, b2, offs, tile_e, tile_m0, list_tok, list_w, ybuf, out, h0, hlen, mode);
    }
    if (mode == 0)
        combine_kernel<<<T_TOK * 128 / 256, 256, 0, stream>>>(ybuf, pos_tk, tok_w, out);
}

// Round 5
// 516.713 us; speedup vs baseline: 1.5162x; 1.5162x over previous
//
#include <hip/hip_runtime.h>
#include <hip/hip_bf16.h>

// MoE: B=4,S=4096,D=512,E=16,H=2048,top-2. T=16384 tokens, 32768 slots.
#define T_TOK 16384
#define DDIM  512
#define NEXP  16
#define HDIM  2048
#define NSLOT (T_TOK * 2)
#define NHB   128         // histogram blocks: NSLOT / 256

#define GBM 128           // gemm tile M
#define GBN 128           // gemm tile N
#define MAXTILE 272       // max m-tiles: 32768/128 + 16

typedef __attribute__((ext_vector_type(8))) short short8;   // 8 x bf16
typedef __attribute__((ext_vector_type(4))) short short4v;
typedef __attribute__((ext_vector_type(4))) float f32x4;

__device__ inline short f2bf(float f) {
    __hip_bfloat16 h = __float2bfloat16(f);
    return *reinterpret_cast<short*>(&h);
}
__device__ inline float geluf(float v) {   // exact gelu
    return 0.5f * v * (1.0f + erff(v * 0.70710678118654752440f));
}
// async global->LDS, 16B per lane. LDS dest = uniform base + lane*16.
__device__ inline void gload16(const void* g, void* l) {
    __builtin_amdgcn_global_load_lds(
        (const __attribute__((address_space(1))) void*)g,
        (__attribute__((address_space(3))) void*)l, 16, 0, 0);
}

// ---------------- routing ----------------
// wave-per-token gate: lane (g,q) = (d-quarter, expert). fp64 throughout
// (tie-robust vs np ref). No LDS, no atomics.
__global__ __launch_bounds__(256) void gate_kernel(
    const float* __restrict__ x, const float* __restrict__ wg,
    const float* __restrict__ bg, int* __restrict__ tok_e,
    float* __restrict__ tok_w)
{
    int wv = threadIdx.x >> 6, lane = threadIdx.x & 63;
    int t = blockIdx.x * 4 + wv;
    int g = lane >> 4, q = lane & 15;
    const float* xr = x + (size_t)t * DDIM + g * 128;
    const float* wr = wg + (size_t)g * 128 * NEXP + q;
    double a0 = 0, a1 = 0, a2 = 0, a3 = 0;
#pragma unroll
    for (int c = 0; c < 8; ++c) {
        float4 v0 = ((const float4*)xr)[c * 4 + 0];
        float4 v1 = ((const float4*)xr)[c * 4 + 1];
        float4 v2 = ((const float4*)xr)[c * 4 + 2];
        float4 v3 = ((const float4*)xr)[c * 4 + 3];
        const float* wp = wr + c * 16 * NEXP;
        a0 += (double)v0.x * (double)wp[0 * NEXP];
        a1 += (double)v0.y * (double)wp[1 * NEXP];
        a2 += (double)v0.z * (double)wp[2 * NEXP];
        a3 += (double)v0.w * (double)wp[3 * NEXP];
        a0 += (double)v1.x * (double)wp[4 * NEXP];
        a1 += (double)v1.y * (double)wp[5 * NEXP];
        a2 += (double)v1.z * (double)wp[6 * NEXP];
        a3 += (double)v1.w * (double)wp[7 * NEXP];
        a0 += (double)v2.x * (double)wp[8 * NEXP];
        a1 += (double)v2.y * (double)wp[9 * NEXP];
        a2 += (double)v2.z * (double)wp[10 * NEXP];
        a3 += (double)v2.w * (double)wp[11 * NEXP];
        a0 += (double)v3.x * (double)wp[12 * NEXP];
        a1 += (double)v3.y * (double)wp[13 * NEXP];
        a2 += (double)v3.z * (double)wp[14 * NEXP];
        a3 += (double)v3.w * (double)wp[15 * NEXP];
    }
    double a = ((a0 + a1) + (a2 + a3));
    a += __shfl_xor(a, 16, 64);
    a += __shfl_xor(a, 32, 64);
    a += (double)bg[q];
    // butterfly argmax over the 16 lanes of each quarter-group (all agree)
    double v0 = a; int i0 = q;
#pragma unroll
    for (int s = 1; s < 16; s <<= 1) {
        double ov = __shfl_xor(v0, s, 64);
        int oi = __shfl_xor(i0, s, 64);
        if (ov > v0 || (ov == v0 && oi < i0)) { v0 = ov; i0 = oi; }
    }
    double m2 = (q == i0) ? -1e300 : a;
    double v1 = m2; int i1 = q;
#pragma unroll
    for (int s = 1; s < 16; s <<= 1) {
        double ov = __shfl_xor(v1, s, 64);
        int oi = __shfl_xor(i1, s, 64);
        if (ov > v1 || (ov == v1 && oi < i1)) { v1 = ov; i1 = oi; }
    }
    if (lane == 0) {
        float ex = expf((float)(v1 - v0));      // <= 1
        float w0 = 1.0f / (1.0f + ex);
        tok_e[2 * t] = i0; tok_e[2 * t + 1] = i1;
        tok_w[2 * t] = w0; tok_w[2 * t + 1] = ex * w0;
    }
}

// per-block expert histogram (LDS atomics only)
__global__ __launch_bounds__(256) void hist_kernel(
    const int* __restrict__ tok_e, int* __restrict__ bhist)
{
    __shared__ int h[NEXP];
    if (threadIdx.x < NEXP) h[threadIdx.x] = 0;
    __syncthreads();
    atomicAdd(&h[tok_e[blockIdx.x * 256 + threadIdx.x]], 1);
    __syncthreads();
    if (threadIdx.x < NEXP) bhist[blockIdx.x * NEXP + threadIdx.x] = h[threadIdx.x];
}

// offs[0..16] = exclusive scan; offs[17] = ntiles; bbase[b][e] = scatter base;
// also builds the compact tile table. Single tiny block.
__global__ void scan_kernel(const int* __restrict__ bhist, int* __restrict__ offs,
                            int* __restrict__ bbase, int* __restrict__ tile_e,
                            int* __restrict__ tile_m0)
{
    int tid = threadIdx.x;
    __shared__ int tot[NEXP];
    if (tid < NEXP) {
        int s = 0;
        for (int b = 0; b < NHB; ++b) s += bhist[b * NEXP + tid];
        tot[tid] = s;
    }
    __syncthreads();
    if (tid == 0) {
        int run = 0;
        for (int e = 0; e < NEXP; ++e) { offs[e] = run; run += tot[e]; }
        offs[NEXP] = run;   // == NSLOT
        int nt = 0;
        for (int e = 0; e < NEXP; ++e)
            for (int m = offs[e]; m < offs[e + 1]; m += GBM) {
                tile_e[nt] = e; tile_m0[nt] = m; ++nt;
            }
        offs[17] = nt;
    }
    __syncthreads();
    if (tid < NEXP) {
        int run = offs[tid];
        for (int b = 0; b < NHB; ++b) {
            bbase[b * NEXP + tid] = run;
            run += bhist[b * NEXP + tid];
        }
    }
}

// local rank via LDS atomic + precomputed block base: no contended global atomics
__global__ __launch_bounds__(256) void scatter_kernel(
    const int* __restrict__ tok_e, const float* __restrict__ tok_w,
    const int* __restrict__ bbase, int* __restrict__ list_tok,
    float* __restrict__ list_w, int* __restrict__ pos_tk)
{
    __shared__ int h[NEXP];
    if (threadIdx.x < NEXP) h[threadIdx.x] = 0;
    __syncthreads();
    int s = blockIdx.x * 256 + threadIdx.x;
    int e = tok_e[s];
    int r = atomicAdd(&h[e], 1);
    int pos = bbase[blockIdx.x * NEXP + e] + r;
    list_tok[pos] = s >> 1;
    list_w[pos] = tok_w[s];
    pos_tk[s] = pos;
}

// ---------------- pre-conversion ----------------

__global__ void cvt_bf16_kernel(const float* __restrict__ src, short* __restrict__ dst, int n4)
{
    int i = blockIdx.x * blockDim.x + threadIdx.x;
    int stride = gridDim.x * blockDim.x;
    for (; i < n4; i += stride) {
        float4 v = ((const float4*)src)[i];
        short4v o;
        o[0] = f2bf(v.x); o[1] = f2bf(v.y); o[2] = f2bf(v.z); o[3] = f2bf(v.w);
        ((short4v*)dst)[i] = o;
    }
}

// transpose one [R][C] fp32 matrix per blockIdx.z into [C][R] bf16
__global__ void wtrans_kernel(const float* __restrict__ src, short* __restrict__ dst, int R, int C)
{
    __shared__ float t[32][33];
    int c0 = blockIdx.x * 32, r0 = blockIdx.y * 32;
    const float* s = src + (size_t)blockIdx.z * R * C;
    short* d = dst + (size_t)blockIdx.z * R * C;
    int cc = threadIdx.x & 31, rr = threadIdx.x >> 5;
#pragma unroll
    for (int pp = 0; pp < 4; ++pp)
        t[rr + pp * 8][cc] = s[(size_t)(r0 + rr + pp * 8) * C + c0 + cc];
    __syncthreads();
#pragma unroll
    for (int pp = 0; pp < 4; ++pp) {
        int c = rr + pp * 8;
        d[(size_t)(c0 + c) * R + r0 + cc] = f2bf(t[cc][c]);
    }
}

// ---------------- expert GEMMs (m97 structure, single-buffer: 4 blk/CU) -------
// 128x128 tile, BK=64, 256 threads = 4 waves (2m x 2n), 64x64 per wave,
// linear LDS, global_load_lds width-16 staging, 2 barriers/K.
// Round-3 lesson: explicit dbuf halves occupancy, regresses (guide m99/m132).
// Round-4 lesson: h-chunking multiplies fp32 ybuf RMW traffic, regresses.

__global__ __launch_bounds__(256) void gemm1_kernel(
    const short* __restrict__ xbf, const short* __restrict__ w1t,
    const float* __restrict__ b1, const int* __restrict__ offs,
    const int* __restrict__ tile_e, const int* __restrict__ tile_m0,
    const int* __restrict__ list_tok, short* __restrict__ hbuf,
    int h0, int hlen)
{
    if ((int)blockIdx.x >= offs[17]) return;
    int e = tile_e[blockIdx.x], m0 = tile_m0[blockIdx.x];
    int rows = offs[e + 1] - m0; if (rows > GBM) rows = GBM;
    int n0 = blockIdx.y * GBN;            // chunk-relative h
    int tid = threadIdx.x, lane = tid & 63, w = tid >> 6;

    __shared__ __align__(16) short As[GBM * 64];
    __shared__ __align__(16) short Bs[GBN * 64];
    __shared__ int ts[GBM];
    if (tid < GBM) ts[tid] = list_tok[m0 + (tid < rows ? tid : rows - 1)];
    __syncthreads();

    // staging: wave w owns LDS rows [w*32, w*32+32); instr i stages 8 rows.
    int srow = w * 32 + (lane >> 3);
    int seg = (lane & 7) * 8;             // k-element offset of this lane's 16B
    const short* ga[4]; const short* gb[4];
#pragma unroll
    for (int i = 0; i < 4; ++i)
        ga[i] = xbf + (size_t)ts[srow + i * 8] * DDIM + seg;
    const short* brow = w1t + ((size_t)e * HDIM + (size_t)(h0 + n0) + srow) * DDIM + seg;
#pragma unroll
    for (int i = 0; i < 4; ++i)
        gb[i] = brow + (size_t)(i * 8) * DDIM;
    short* lA = As + w * 2048;
    short* lB = Bs + w * 2048;

    int wm = w >> 1, wn = w & 1;
    int a_r = wm * 64 + (lane & 15);
    int b_r = wn * 64 + (lane & 15);
    int kf = (lane >> 4) * 8;

    f32x4 vzero = {0.0f, 0.0f, 0.0f, 0.0f};
    f32x4 acc[4][4];
#pragma unroll
    for (int i = 0; i < 4; ++i)
#pragma unroll
        for (int j = 0; j < 4; ++j) acc[i][j] = vzero;

#pragma unroll 1
    for (int kb = 0; kb < DDIM / 64; ++kb) {
#pragma unroll
        for (int i = 0; i < 4; ++i) gload16(ga[i] + kb * 64, lA + i * 512);
#pragma unroll
        for (int i = 0; i < 4; ++i) gload16(gb[i] + kb * 64, lB + i * 512);
        __syncthreads();
#pragma unroll
        for (int ks = 0; ks < 2; ++ks) {
            short8 af[4], bfv[4];
            int ko = ks * 32 + kf;
#pragma unroll
            for (int mi = 0; mi < 4; ++mi)
                af[mi] = *(const short8*)(As + (a_r + mi * 16) * 64 + ko);
#pragma unroll
            for (int ni = 0; ni < 4; ++ni)
                bfv[ni] = *(const short8*)(Bs + (b_r + ni * 16) * 64 + ko);
#pragma unroll
            for (int mi = 0; mi < 4; ++mi)
#pragma unroll
                for (int ni = 0; ni < 4; ++ni)
                    acc[mi][ni] = __builtin_amdgcn_mfma_f32_16x16x32_bf16(
                        af[mi], bfv[ni], acc[mi][ni], 0, 0, 0);
        }
        __syncthreads();
    }

    int crow = wm * 64 + ((lane >> 4) << 2);
    int ccol = wn * 64 + (lane & 15);
#pragma unroll
    for (int mi = 0; mi < 4; ++mi) {
#pragma unroll
        for (int ni = 0; ni < 4; ++ni) {
            int col = ccol + ni * 16;
            float bias = b1[e * HDIM + h0 + n0 + col];
#pragma unroll
            for (int j = 0; j < 4; ++j) {
                int row = crow + mi * 16 + j;
                if (row < rows) {
                    float v = acc[mi][ni][j] + bias;
                    hbuf[(size_t)(m0 + row) * hlen + (n0 + col)] = f2bf(geluf(v));
                }
            }
        }
    }
}

__global__ __launch_bounds__(256) void gemm2_kernel(
    const short* __restrict__ hbuf, const short* __restrict__ w2t,
    const float* __restrict__ b2, const int* __restrict__ offs,
    const int* __restrict__ tile_e, const int* __restrict__ tile_m0,
    const int* __restrict__ list_tok, const float* __restrict__ list_w,
    float* __restrict__ ybuf, float* __restrict__ out,
    int h0, int hlen, int mode)
{
    if ((int)blockIdx.x >= offs[17]) return;
    int e = tile_e[blockIdx.x], m0 = tile_m0[blockIdx.x];
    int rows = offs[e + 1] - m0; if (rows > GBM) rows = GBM;
    int n0 = blockIdx.y * GBN;            // output d coordinate
    int tid = threadIdx.x, lane = tid & 63, w = tid >> 6;

    __shared__ __align__(16) short As[GBM * 64];
    __shared__ __align__(16) short Bs[GBN * 64];
    __shared__ int ts[GBM];
    __shared__ float lw[GBM];
    if (tid < GBM) {
        int idx = m0 + (tid < rows ? tid : rows - 1);
        ts[tid] = list_tok[idx];
        lw[tid] = list_w[idx];
    }
    __syncthreads();

    int srow = w * 32 + (lane >> 3);
    int seg = (lane & 7) * 8;
    const short* ga[4]; const short* gb[4];
#pragma unroll
    for (int i = 0; i < 4; ++i) {
        int slot = m0 + srow + i * 8; if (slot >= NSLOT) slot = NSLOT - 1;
        ga[i] = hbuf + (size_t)slot * hlen + seg;
    }
    const short* brow = w2t + ((size_t)e * DDIM + n0 + srow) * HDIM + h0 + seg;
#pragma unroll
    for (int i = 0; i < 4; ++i)
        gb[i] = brow + (size_t)(i * 8) * HDIM;
    short* lA = As + w * 2048;
    short* lB = Bs + w * 2048;

    int wm = w >> 1, wn = w & 1;
    int a_r = wm * 64 + (lane & 15);
    int b_r = wn * 64 + (lane & 15);
    int kf = (lane >> 4) * 8;

    f32x4 vzero = {0.0f, 0.0f, 0.0f, 0.0f};
    f32x4 acc[4][4];
#pragma unroll
    for (int i = 0; i < 4; ++i)
#pragma unroll
        for (int j = 0; j < 4; ++j) acc[i][j] = vzero;

    int nkb = hlen >> 6;
#pragma unroll 1
    for (int kb = 0; kb < nkb; ++kb) {
#pragma unroll
        for (int i = 0; i < 4; ++i) gload16(ga[i] + kb * 64, lA + i * 512);
#pragma unroll
        for (int i = 0; i < 4; ++i) gload16(gb[i] + kb * 64, lB + i * 512);
        __syncthreads();
#pragma unroll
        for (int ks = 0; ks < 2; ++ks) {
            short8 af[4], bfv[4];
            int ko = ks * 32 + kf;
#pragma unroll
            for (int mi = 0; mi < 4; ++mi)
                af[mi] = *(const short8*)(As + (a_r + mi * 16) * 64 + ko);
#pragma unroll
            for (int ni = 0; ni < 4; ++ni)
                bfv[ni] = *(const short8*)(Bs + (b_r + ni * 16) * 64 + ko);
#pragma unroll
            for (int mi = 0; mi < 4; ++mi)
#pragma unroll
                for (int ni = 0; ni < 4; ++ni)
                    acc[mi][ni] = __builtin_amdgcn_mfma_f32_16x16x32_bf16(
                        af[mi], bfv[ni], acc[mi][ni], 0, 0, 0);
        }
        __syncthreads();
    }

    int crow = wm * 64 + ((lane >> 4) << 2);
    int ccol = wn * 64 + (lane & 15);
#pragma unroll
    for (int mi = 0; mi < 4; ++mi) {
#pragma unroll
        for (int ni = 0; ni < 4; ++ni) {
            int col = ccol + ni * 16;
            float bias = (h0 == 0) ? b2[e * DDIM + n0 + col] : 0.0f;
#pragma unroll
            for (int j = 0; j < 4; ++j) {
                int row = crow + mi * 16 + j;
                if (row < rows) {
                    float v = acc[mi][ni][j] + bias;
                    if (mode == 0) {
                        float* yp = ybuf + (size_t)(m0 + row) * DDIM + n0 + col;
                        *yp = (h0 == 0) ? v : (*yp + v);
                    } else {
                        atomicAdd(&out[(size_t)ts[row] * DDIM + n0 + col], lw[row] * v);
                    }
                }
            }
        }
    }
}

// out[t] = w0*ybuf[pos0] + w1*ybuf[pos1]
__global__ __launch_bounds__(256) void combine_kernel(
    const float* __restrict__ ybuf, const int* __restrict__ pos_tk,
    const float* __restrict__ tok_w, float* __restrict__ out)
{
    int i = blockIdx.x * 256 + threadIdx.x;   // over T_TOK * 128 float4 units
    int t = i >> 7, c = i & 127;
    float w0 = tok_w[2 * t], w1 = tok_w[2 * t + 1];
    int p0 = pos_tk[2 * t], p1 = pos_tk[2 * t + 1];
    float4 a = ((const float4*)ybuf)[(size_t)p0 * 128 + c];
    float4 b = ((const float4*)ybuf)[(size_t)p1 * 128 + c];
    float4 o;
    o.x = w0 * a.x + w1 * b.x;
    o.y = w0 * a.y + w1 * b.y;
    o.z = w0 * a.z + w1 * b.z;
    o.w = w0 * a.w + w1 * b.w;
    ((float4*)out)[(size_t)t * 128 + c] = o;
}

// ---------------- launch ----------------

extern "C" void kernel_launch(void* const* d_in, const int* in_sizes, int n_in,
                              void* d_out, int out_size, void* d_ws, size_t ws_size,
                              hipStream_t stream)
{
    const float* x  = (const float*)d_in[0];
    const float* wg = (const float*)d_in[1];
    const float* bg = (const float*)d_in[2];
    const float* w1 = (const float*)d_in[3];
    const float* b1 = (const float*)d_in[4];
    const float* w2 = (const float*)d_in[5];
    const float* b2 = (const float*)d_in[6];
    float* out = (float*)d_out;

    char* p = (char*)d_ws;
    int* offs     = (int*)(p + 128);            // 32 ints
    int* tile_e   = (int*)(p + 256);            // 512 ints
    int* tile_m0  = (int*)(p + 2304);           // 512 ints
    int* bhist    = (int*)(p + 8192);           // NHB*16 ints = 8 KiB
    int* bbase    = (int*)(p + 16384);          // 8 KiB
    int* tok_e    = (int*)(p + 32768);          // 128 KiB
    float* tok_w  = (float*)(p + 32768 + 131072);
    int* list_tok = (int*)(p + 32768 + 262144);
    float* list_w = (float*)(p + 32768 + 393216);
    int* pos_tk   = (int*)(p + 32768 + 524288);
    short* xbf    = (short*)(p + 32768 + 655360);             // 16 MiB
    short* w1t    = xbf + (size_t)T_TOK * DDIM;               // 32 MiB
    short* w2t    = w1t + (size_t)NEXP * DDIM * HDIM;         // 32 MiB
    char* after   = (char*)(w2t + (size_t)NEXP * DDIM * HDIM);
    size_t fixed  = (size_t)(after - p);

    // hlen=2048 (single chunk) preferred: round-4 measured that h-chunking
    // multiplies ybuf fp32 RMW traffic and regresses.
    static const int pref[5] = {2048, 1024, 512, 256, 128};
    int hlen = 0, mode = 0;
    for (int i = 0; i < 5; ++i) {
        int hl = pref[i];
        if (fixed + (size_t)NSLOT * DDIM * 4 + (size_t)NSLOT * hl * 2 <= ws_size) { hlen = hl; mode = 0; break; }
    }
    if (!hlen)
        for (int i = 0; i < 5; ++i) {
            int hl = pref[i];
            if (fixed + (size_t)NSLOT * hl * 2 <= ws_size) { hlen = hl; mode = 1; break; }
        }

    float* ybuf = (float*)after;
    short* hbuf = (mode == 0) ? (short*)(after + (size_t)NSLOT * DDIM * 4) : (short*)after;

    if (!hlen) { hipMemsetAsync(d_out, 0, (size_t)out_size * sizeof(float), stream); return; }
    if (mode == 1) hipMemsetAsync(d_out, 0, (size_t)out_size * sizeof(float), stream);

    gate_kernel<<<T_TOK / 4, 256, 0, stream>>>(x, wg, bg, tok_e, tok_w);
    hist_kernel<<<NHB, 256, 0, stream>>>(tok_e, bhist);
    scan_kernel<<<1, 64, 0, stream>>>(bhist, offs, bbase, tile_e, tile_m0);
    scatter_kernel<<<NHB, 256, 0, stream>>>(tok_e, tok_w, bbase, list_tok, list_w, pos_tk);
    cvt_bf16_kernel<<<2048, 256, 0, stream>>>(x, xbf, T_TOK * DDIM / 4);
    wtrans_kernel<<<dim3(HDIM / 32, DDIM / 32, NEXP), 256, 0, stream>>>(w1, w1t, DDIM, HDIM);
    wtrans_kernel<<<dim3(DDIM / 32, HDIM / 32, NEXP), 256, 0, stream>>>(w2, w2t, HDIM, DDIM);

    for (int h0 = 0; h0 < HDIM; h0 += hlen) {
        gemm1_kernel<<<dim3(MAXTILE, hlen / GBN), 256, 0, stream>>>(
            xbf, w1t, b1, offs, tile_e, tile_m0, list_tok, hbuf, h0, hlen);
        gemm2_kernel<<<dim3(MAXTILE, DDIM / GBN), 256, 0, stream>>>(
            hbuf, w2t, b2, offs, tile_e, tile_m0, list_tok, list_w, ybuf, out, h0, hlen, mode);
    }
    if (mode == 0)
        combine_kernel<<<T_TOK * 128 / 256, 256, 0, stream>>>(ybuf, pos_tk, tok_w, out);
}

// Round 6
// 505.953 us; speedup vs baseline: 1.5485x; 1.0213x over previous
//
#include <hip/hip_runtime.h>
#include <hip/hip_bf16.h>

// MoE: B=4,S=4096,D=512,E=16,H=2048,top-2. T=16384 tokens, 32768 slots.
#define T_TOK 16384
#define DDIM  512
#define NEXP  16
#define HDIM  2048
#define NSLOT (T_TOK * 2)
#define NHB   128         // histogram blocks: NSLOT / 256

#define GBM 128           // gemm tile M (matches tile table)
#define GBN 256           // gemm tile N
#define BK  32            // gemm K-step
#define MAXTILE 272       // max m-tiles: 32768/128 + 16

typedef __attribute__((ext_vector_type(8))) short short8;   // 8 x bf16
typedef __attribute__((ext_vector_type(4))) short short4v;
typedef __attribute__((ext_vector_type(4))) float f32x4;

__device__ inline short f2bf(float f) {
    __hip_bfloat16 h = __float2bfloat16(f);
    return *reinterpret_cast<short*>(&h);
}
__device__ inline float geluf(float v) {   // exact gelu
    return 0.5f * v * (1.0f + erff(v * 0.70710678118654752440f));
}
// async global->LDS, 16B per lane. LDS dest = WAVE-UNIFORM base + lane*16.
__device__ inline void gload16(const void* g, void* l) {
    __builtin_amdgcn_global_load_lds(
        (const __attribute__((address_space(1))) void*)g,
        (__attribute__((address_space(3))) void*)l, 16, 0, 0);
}

// ---------------- routing ----------------
// wave-per-token gate: lane (g,q) = (d-quarter, expert). fp64 (tie-robust).
__global__ __launch_bounds__(256) void gate_kernel(
    const float* __restrict__ x, const float* __restrict__ wg,
    const float* __restrict__ bg, int* __restrict__ tok_e,
    float* __restrict__ tok_w)
{
    int wv = threadIdx.x >> 6, lane = threadIdx.x & 63;
    int t = blockIdx.x * 4 + wv;
    int g = lane >> 4, q = lane & 15;
    const float* xr = x + (size_t)t * DDIM + g * 128;
    const float* wr = wg + (size_t)g * 128 * NEXP + q;
    double a0 = 0, a1 = 0, a2 = 0, a3 = 0;
#pragma unroll
    for (int c = 0; c < 8; ++c) {
        float4 v0 = ((const float4*)xr)[c * 4 + 0];
        float4 v1 = ((const float4*)xr)[c * 4 + 1];
        float4 v2 = ((const float4*)xr)[c * 4 + 2];
        float4 v3 = ((const float4*)xr)[c * 4 + 3];
        const float* wp = wr + c * 16 * NEXP;
        a0 += (double)v0.x * (double)wp[0 * NEXP];
        a1 += (double)v0.y * (double)wp[1 * NEXP];
        a2 += (double)v0.z * (double)wp[2 * NEXP];
        a3 += (double)v0.w * (double)wp[3 * NEXP];
        a0 += (double)v1.x * (double)wp[4 * NEXP];
        a1 += (double)v1.y * (double)wp[5 * NEXP];
        a2 += (double)v1.z * (double)wp[6 * NEXP];
        a3 += (double)v1.w * (double)wp[7 * NEXP];
        a0 += (double)v2.x * (double)wp[8 * NEXP];
        a1 += (double)v2.y * (double)wp[9 * NEXP];
        a2 += (double)v2.z * (double)wp[10 * NEXP];
        a3 += (double)v2.w * (double)wp[11 * NEXP];
        a0 += (double)v3.x * (double)wp[12 * NEXP];
        a1 += (double)v3.y * (double)wp[13 * NEXP];
        a2 += (double)v3.z * (double)wp[14 * NEXP];
        a3 += (double)v3.w * (double)wp[15 * NEXP];
    }
    double a = ((a0 + a1) + (a2 + a3));
    a += __shfl_xor(a, 16, 64);
    a += __shfl_xor(a, 32, 64);
    a += (double)bg[q];
    double v0 = a; int i0 = q;
#pragma unroll
    for (int s = 1; s < 16; s <<= 1) {
        double ov = __shfl_xor(v0, s, 64);
        int oi = __shfl_xor(i0, s, 64);
        if (ov > v0 || (ov == v0 && oi < i0)) { v0 = ov; i0 = oi; }
    }
    double m2 = (q == i0) ? -1e300 : a;
    double v1 = m2; int i1 = q;
#pragma unroll
    for (int s = 1; s < 16; s <<= 1) {
        double ov = __shfl_xor(v1, s, 64);
        int oi = __shfl_xor(i1, s, 64);
        if (ov > v1 || (ov == v1 && oi < i1)) { v1 = ov; i1 = oi; }
    }
    if (lane == 0) {
        float ex = expf((float)(v1 - v0));      // <= 1
        float w0 = 1.0f / (1.0f + ex);
        tok_e[2 * t] = i0; tok_e[2 * t + 1] = i1;
        tok_w[2 * t] = w0; tok_w[2 * t + 1] = ex * w0;
    }
}

// per-block expert histogram (LDS atomics only)
__global__ __launch_bounds__(256) void hist_kernel(
    const int* __restrict__ tok_e, int* __restrict__ bhist)
{
    __shared__ int h[NEXP];
    if (threadIdx.x < NEXP) h[threadIdx.x] = 0;
    __syncthreads();
    atomicAdd(&h[tok_e[blockIdx.x * 256 + threadIdx.x]], 1);
    __syncthreads();
    if (threadIdx.x < NEXP) bhist[blockIdx.x * NEXP + threadIdx.x] = h[threadIdx.x];
}

// offs[0..16] = exclusive scan; offs[17] = ntiles; bbase[b][e] = scatter base.
__global__ void scan_kernel(const int* __restrict__ bhist, int* __restrict__ offs,
                            int* __restrict__ bbase, int* __restrict__ tile_e,
                            int* __restrict__ tile_m0)
{
    int tid = threadIdx.x;
    __shared__ int tot[NEXP];
    if (tid < NEXP) {
        int s = 0;
        for (int b = 0; b < NHB; ++b) s += bhist[b * NEXP + tid];
        tot[tid] = s;
    }
    __syncthreads();
    if (tid == 0) {
        int run = 0;
        for (int e = 0; e < NEXP; ++e) { offs[e] = run; run += tot[e]; }
        offs[NEXP] = run;   // == NSLOT
        int nt = 0;
        for (int e = 0; e < NEXP; ++e)
            for (int m = offs[e]; m < offs[e + 1]; m += GBM) {
                tile_e[nt] = e; tile_m0[nt] = m; ++nt;
            }
        offs[17] = nt;
    }
    __syncthreads();
    if (tid < NEXP) {
        int run = offs[tid];
        for (int b = 0; b < NHB; ++b) {
            bbase[b * NEXP + tid] = run;
            run += bhist[b * NEXP + tid];
        }
    }
}

// local rank via LDS atomic + precomputed block base
__global__ __launch_bounds__(256) void scatter_kernel(
    const int* __restrict__ tok_e, const float* __restrict__ tok_w,
    const int* __restrict__ bbase, int* __restrict__ list_tok,
    float* __restrict__ list_w, int* __restrict__ pos_tk)
{
    __shared__ int h[NEXP];
    if (threadIdx.x < NEXP) h[threadIdx.x] = 0;
    __syncthreads();
    int s = blockIdx.x * 256 + threadIdx.x;
    int e = tok_e[s];
    int r = atomicAdd(&h[e], 1);
    int pos = bbase[blockIdx.x * NEXP + e] + r;
    list_tok[pos] = s >> 1;
    list_w[pos] = tok_w[s];
    pos_tk[s] = pos;
}

// ---------------- pre-conversion ----------------

__global__ void cvt_bf16_kernel(const float* __restrict__ src, short* __restrict__ dst, int n4)
{
    int i = blockIdx.x * blockDim.x + threadIdx.x;
    int stride = gridDim.x * blockDim.x;
    for (; i < n4; i += stride) {
        float4 v = ((const float4*)src)[i];
        short4v o;
        o[0] = f2bf(v.x); o[1] = f2bf(v.y); o[2] = f2bf(v.z); o[3] = f2bf(v.w);
        ((short4v*)dst)[i] = o;
    }
}

// transpose one [R][C] fp32 matrix per blockIdx.z into [C][R] bf16
__global__ void wtrans_kernel(const float* __restrict__ src, short* __restrict__ dst, int R, int C)
{
    __shared__ float t[32][33];
    int c0 = blockIdx.x * 32, r0 = blockIdx.y * 32;
    const float* s = src + (size_t)blockIdx.z * R * C;
    short* d = dst + (size_t)blockIdx.z * R * C;
    int cc = threadIdx.x & 31, rr = threadIdx.x >> 5;
#pragma unroll
    for (int pp = 0; pp < 4; ++pp)
        t[rr + pp * 8][cc] = s[(size_t)(r0 + rr + pp * 8) * C + c0 + cc];
    __syncthreads();
#pragma unroll
    for (int pp = 0; pp < 4; ++pp) {
        int c = rr + pp * 8;
        d[(size_t)(c0 + c) * R + r0 + cc] = f2bf(t[cc][c]);
    }
}

// ---------------- expert GEMMs: counted-vmcnt 3-buffer pipeline ----------------
// 128x256 tile, BK=32, 512 threads = 8 waves (2M x 4N), 64x64 per wave.
// LDS: 3 bufs x (A 8KB + B 16KB) = 72 KB -> 2 blocks/CU.
// Per K-step: vmcnt(3) [counted, never 0 in steady state] -> raw s_barrier ->
// sched_barrier(0) -> stage(t+2) -> 8 ds_read_b128 -> setprio-wrapped 16 MFMA.
// ONE barrier per K-step. T2 swizzle via pre-swizzled gather source:
// phys 16B slot = logical ^ ((row>>1)&3), same involution on read.
// Safety: reads of tile t-1 finish before a wave reaches barrier t (lgkmcnt
// before its MFMAs); stage(t+2) overwrites buf[(t-1)%3] only after barrier t.

#define PRO_FRAG_OFFS(aoff, boff)                                        \
    int l15 = l & 15, kq = l >> 4;                                       \
    int aoff[4], boff[4];                                                \
    _Pragma("unroll")                                                    \
    for (int mi = 0; mi < 4; ++mi) {                                     \
        int R = (w >> 2) * 64 + mi * 16 + l15;                           \
        aoff[mi] = R * BK + ((kq ^ ((R >> 1) & 3)) * 8);                 \
    }                                                                    \
    _Pragma("unroll")                                                    \
    for (int ni = 0; ni < 4; ++ni) {                                     \
        int S = (w & 3) * 64 + ni * 16 + l15;                            \
        boff[ni] = S * BK + ((kq ^ ((S >> 1) & 3)) * 8);                 \
    }

__global__ __launch_bounds__(512) void gemm1_kernel(
    const short* __restrict__ xbf, const short* __restrict__ w1t,
    const float* __restrict__ b1, const int* __restrict__ offs,
    const int* __restrict__ tile_e, const int* __restrict__ tile_m0,
    const int* __restrict__ list_tok, short* __restrict__ hbuf,
    int h0, int hlen)
{
    if ((int)blockIdx.x >= offs[17]) return;
    int e = tile_e[blockIdx.x], m0 = tile_m0[blockIdx.x];
    int rows = offs[e + 1] - m0; if (rows > GBM) rows = GBM;
    int n0 = blockIdx.y * GBN;
    int tid = threadIdx.x, l = tid & 63, w = tid >> 6;

    __shared__ __align__(16) short As[3][GBM * BK];   // 3 x 8 KiB
    __shared__ __align__(16) short Bs[3][GBN * BK];   // 3 x 16 KiB
    __shared__ int ts[GBM];
    if (tid < GBM) ts[tid] = list_tok[m0 + (tid < rows ? tid : rows - 1)];
    __syncthreads();

    // staging: A region w = rows [w*16,+16); B regions w*2+j. lane l -> row +l/4,
    // phys slot l&3; fetch global LOGICAL slot (l&3)^((row>>1)&3)  [T2 source-swz]
    int arow = w * 16 + (l >> 2);
    int aslot = (l & 3) ^ ((arow >> 1) & 3);
    const short* gA = xbf + (size_t)ts[arow] * DDIM + aslot * 8;
    int brow0 = (w * 2 + 0) * 16 + (l >> 2);
    int brow1 = (w * 2 + 1) * 16 + (l >> 2);
    int bs0 = (l & 3) ^ ((brow0 >> 1) & 3);
    int bs1 = (l & 3) ^ ((brow1 >> 1) & 3);
    const short* gB0 = w1t + ((size_t)e * HDIM + (size_t)(h0 + n0 + brow0)) * DDIM + bs0 * 8;
    const short* gB1 = w1t + ((size_t)e * HDIM + (size_t)(h0 + n0 + brow1)) * DDIM + bs1 * 8;

    PRO_FRAG_OFFS(aoff, boff)

    f32x4 vzero = {0.0f, 0.0f, 0.0f, 0.0f};
    f32x4 acc[4][4];
#pragma unroll
    for (int i = 0; i < 4; ++i)
#pragma unroll
        for (int j = 0; j < 4; ++j) acc[i][j] = vzero;

#define STAGE1(T, B) {                                            \
        gload16(gA  + (T) * BK, &As[B][w * 512]);                 \
        gload16(gB0 + (T) * BK, &Bs[B][(w * 2 + 0) * 512]);       \
        gload16(gB1 + (T) * BK, &Bs[B][(w * 2 + 1) * 512]); }

    const int nt = DDIM / BK;          // 16
    STAGE1(0, 0);
    STAGE1(1, 1);
    int cb = 0, sb = 2;
#pragma unroll 1
    for (int t = 0; t < nt; ++t) {
        if (t < nt - 1) asm volatile("s_waitcnt vmcnt(3)" ::: "memory");
        else            asm volatile("s_waitcnt vmcnt(0)" ::: "memory");
        __builtin_amdgcn_s_barrier();
        __builtin_amdgcn_sched_barrier(0);
        if (t + 2 < nt) STAGE1(t + 2, sb);
        const short* Ab = &As[cb][0];
        const short* Bb = &Bs[cb][0];
        short8 af[4], bv[4];
#pragma unroll
        for (int mi = 0; mi < 4; ++mi) af[mi] = *(const short8*)(Ab + aoff[mi]);
#pragma unroll
        for (int ni = 0; ni < 4; ++ni) bv[ni] = *(const short8*)(Bb + boff[ni]);
        __builtin_amdgcn_s_setprio(1);
#pragma unroll
        for (int mi = 0; mi < 4; ++mi)
#pragma unroll
            for (int ni = 0; ni < 4; ++ni)
                acc[mi][ni] = __builtin_amdgcn_mfma_f32_16x16x32_bf16(
                    af[mi], bv[ni], acc[mi][ni], 0, 0, 0);
        __builtin_amdgcn_s_setprio(0);
        cb = (cb == 2) ? 0 : cb + 1;
        sb = (sb == 2) ? 0 : sb + 1;
    }
#undef STAGE1

    int crow = (w >> 2) * 64 + ((l >> 4) << 2);
    int ccol = (w & 3) * 64 + (l & 15);
#pragma unroll
    for (int mi = 0; mi < 4; ++mi) {
#pragma unroll
        for (int ni = 0; ni < 4; ++ni) {
            int col = ccol + ni * 16;
            float bias = b1[e * HDIM + h0 + n0 + col];
#pragma unroll
            for (int j = 0; j < 4; ++j) {
                int row = crow + mi * 16 + j;
                if (row < rows) {
                    float v = acc[mi][ni][j] + bias;
                    hbuf[(size_t)(m0 + row) * hlen + (n0 + col)] = f2bf(geluf(v));
                }
            }
        }
    }
}

__global__ __launch_bounds__(512) void gemm2_kernel(
    const short* __restrict__ hbuf, const short* __restrict__ w2t,
    const float* __restrict__ b2, const int* __restrict__ offs,
    const int* __restrict__ tile_e, const int* __restrict__ tile_m0,
    const int* __restrict__ list_tok, const float* __restrict__ list_w,
    float* __restrict__ ybuf, float* __restrict__ out,
    int h0, int hlen, int mode)
{
    if ((int)blockIdx.x >= offs[17]) return;
    int e = tile_e[blockIdx.x], m0 = tile_m0[blockIdx.x];
    int rows = offs[e + 1] - m0; if (rows > GBM) rows = GBM;
    int n0 = blockIdx.y * GBN;            // output d coordinate
    int tid = threadIdx.x, l = tid & 63, w = tid >> 6;

    __shared__ __align__(16) short As[3][GBM * BK];
    __shared__ __align__(16) short Bs[3][GBN * BK];
    __shared__ int ts[GBM];
    __shared__ float lw[GBM];
    if (tid < GBM) {
        int idx = m0 + (tid < rows ? tid : rows - 1);
        ts[tid] = list_tok[idx];
        lw[tid] = list_w[idx];
    }
    __syncthreads();

    int arow = w * 16 + (l >> 2);
    int aslot = (l & 3) ^ ((arow >> 1) & 3);
    int aslotg = m0 + arow; if (aslotg >= NSLOT) aslotg = NSLOT - 1;
    const short* gA = hbuf + (size_t)aslotg * hlen + aslot * 8;
    int brow0 = (w * 2 + 0) * 16 + (l >> 2);
    int brow1 = (w * 2 + 1) * 16 + (l >> 2);
    int bs0 = (l & 3) ^ ((brow0 >> 1) & 3);
    int bs1 = (l & 3) ^ ((brow1 >> 1) & 3);
    const short* gB0 = w2t + ((size_t)e * DDIM + (size_t)(n0 + brow0)) * HDIM + h0 + bs0 * 8;
    const short* gB1 = w2t + ((size_t)e * DDIM + (size_t)(n0 + brow1)) * HDIM + h0 + bs1 * 8;

    PRO_FRAG_OFFS(aoff, boff)

    f32x4 vzero = {0.0f, 0.0f, 0.0f, 0.0f};
    f32x4 acc[4][4];
#pragma unroll
    for (int i = 0; i < 4; ++i)
#pragma unroll
        for (int j = 0; j < 4; ++j) acc[i][j] = vzero;

#define STAGE2(T, B) {                                            \
        gload16(gA  + (T) * BK, &As[B][w * 512]);                 \
        gload16(gB0 + (T) * BK, &Bs[B][(w * 2 + 0) * 512]);       \
        gload16(gB1 + (T) * BK, &Bs[B][(w * 2 + 1) * 512]); }

    const int nt = hlen / BK;          // 64 at hlen=2048
    STAGE2(0, 0);
    STAGE2(1, 1);
    int cb = 0, sb = 2;
#pragma unroll 1
    for (int t = 0; t < nt; ++t) {
        if (t < nt - 1) asm volatile("s_waitcnt vmcnt(3)" ::: "memory");
        else            asm volatile("s_waitcnt vmcnt(0)" ::: "memory");
        __builtin_amdgcn_s_barrier();
        __builtin_amdgcn_sched_barrier(0);
        if (t + 2 < nt) STAGE2(t + 2, sb);
        const short* Ab = &As[cb][0];
        const short* Bb = &Bs[cb][0];
        short8 af[4], bv[4];
#pragma unroll
        for (int mi = 0; mi < 4; ++mi) af[mi] = *(const short8*)(Ab + aoff[mi]);
#pragma unroll
        for (int ni = 0; ni < 4; ++ni) bv[ni] = *(const short8*)(Bb + boff[ni]);
        __builtin_amdgcn_s_setprio(1);
#pragma unroll
        for (int mi = 0; mi < 4; ++mi)
#pragma unroll
            for (int ni = 0; ni < 4; ++ni)
                acc[mi][ni] = __builtin_amdgcn_mfma_f32_16x16x32_bf16(
                    af[mi], bv[ni], acc[mi][ni], 0, 0, 0);
        __builtin_amdgcn_s_setprio(0);
        cb = (cb == 2) ? 0 : cb + 1;
        sb = (sb == 2) ? 0 : sb + 1;
    }
#undef STAGE2

    int crow = (w >> 2) * 64 + ((l >> 4) << 2);
    int ccol = (w & 3) * 64 + (l & 15);
#pragma unroll
    for (int mi = 0; mi < 4; ++mi) {
#pragma unroll
        for (int ni = 0; ni < 4; ++ni) {
            int col = ccol + ni * 16;
            float bias = (h0 == 0) ? b2[e * DDIM + n0 + col] : 0.0f;
#pragma unroll
            for (int j = 0; j < 4; ++j) {
                int row = crow + mi * 16 + j;
                if (row < rows) {
                    float v = acc[mi][ni][j] + bias;
                    if (mode == 0) {
                        float* yp = ybuf + (size_t)(m0 + row) * DDIM + n0 + col;
                        *yp = (h0 == 0) ? v : (*yp + v);
                    } else {
                        atomicAdd(&out[(size_t)ts[row] * DDIM + n0 + col], lw[row] * v);
                    }
                }
            }
        }
    }
}

// out[t] = w0*ybuf[pos0] + w1*ybuf[pos1]
__global__ __launch_bounds__(256) void combine_kernel(
    const float* __restrict__ ybuf, const int* __restrict__ pos_tk,
    const float* __restrict__ tok_w, float* __restrict__ out)
{
    int i = blockIdx.x * 256 + threadIdx.x;   // over T_TOK * 128 float4 units
    int t = i >> 7, c = i & 127;
    float w0 = tok_w[2 * t], w1 = tok_w[2 * t + 1];
    int p0 = pos_tk[2 * t], p1 = pos_tk[2 * t + 1];
    float4 a = ((const float4*)ybuf)[(size_t)p0 * 128 + c];
    float4 b = ((const float4*)ybuf)[(size_t)p1 * 128 + c];
    float4 o;
    o.x = w0 * a.x + w1 * b.x;
    o.y = w0 * a.y + w1 * b.y;
    o.z = w0 * a.z + w1 * b.z;
    o.w = w0 * a.w + w1 * b.w;
    ((float4*)out)[(size_t)t * 128 + c] = o;
}

// ---------------- launch ----------------

extern "C" void kernel_launch(void* const* d_in, const int* in_sizes, int n_in,
                              void* d_out, int out_size, void* d_ws, size_t ws_size,
                              hipStream_t stream)
{
    const float* x  = (const float*)d_in[0];
    const float* wg = (const float*)d_in[1];
    const float* bg = (const float*)d_in[2];
    const float* w1 = (const float*)d_in[3];
    const float* b1 = (const float*)d_in[4];
    const float* w2 = (const float*)d_in[5];
    const float* b2 = (const float*)d_in[6];
    float* out = (float*)d_out;

    char* p = (char*)d_ws;
    int* offs     = (int*)(p + 128);            // 32 ints
    int* tile_e   = (int*)(p + 256);            // 512 ints
    int* tile_m0  = (int*)(p + 2304);           // 512 ints
    int* bhist    = (int*)(p + 8192);           // 8 KiB
    int* bbase    = (int*)(p + 16384);          // 8 KiB
    int* tok_e    = (int*)(p + 32768);          // 128 KiB
    float* tok_w  = (float*)(p + 32768 + 131072);
    int* list_tok = (int*)(p + 32768 + 262144);
    float* list_w = (float*)(p + 32768 + 393216);
    int* pos_tk   = (int*)(p + 32768 + 524288);
    short* xbf    = (short*)(p + 32768 + 655360);             // 16 MiB
    short* w1t    = xbf + (size_t)T_TOK * DDIM;               // 32 MiB
    short* w2t    = w1t + (size_t)NEXP * DDIM * HDIM;         // 32 MiB
    char* after   = (char*)(w2t + (size_t)NEXP * DDIM * HDIM);
    size_t fixed  = (size_t)(after - p);

    // hlen=2048 (single chunk): round-4 showed h-chunking multiplies ybuf RMW.
    static const int pref[5] = {2048, 1024, 512, 256, 128};
    int hlen = 0, mode = 0;
    for (int i = 0; i < 5; ++i) {
        int hl = pref[i];
        if (fixed + (size_t)NSLOT * DDIM * 4 + (size_t)NSLOT * hl * 2 <= ws_size) { hlen = hl; mode = 0; break; }
    }
    if (!hlen)
        for (int i = 0; i < 5; ++i) {
            int hl = pref[i];
            if (fixed + (size_t)NSLOT * hl * 2 <= ws_size) { hlen = hl; mode = 1; break; }
        }

    float* ybuf = (float*)after;
    short* hbuf = (mode == 0) ? (short*)(after + (size_t)NSLOT * DDIM * 4) : (short*)after;

    if (!hlen) { hipMemsetAsync(d_out, 0, (size_t)out_size * sizeof(float), stream); return; }
    if (mode == 1) hipMemsetAsync(d_out, 0, (size_t)out_size * sizeof(float), stream);

    gate_kernel<<<T_TOK / 4, 256, 0, stream>>>(x, wg, bg, tok_e, tok_w);
    hist_kernel<<<NHB, 256, 0, stream>>>(tok_e, bhist);
    scan_kernel<<<1, 64, 0, stream>>>(bhist, offs, bbase, tile_e, tile_m0);
    scatter_kernel<<<NHB, 256, 0, stream>>>(tok_e, tok_w, bbase, list_tok, list_w, pos_tk);
    cvt_bf16_kernel<<<2048, 256, 0, stream>>>(x, xbf, T_TOK * DDIM / 4);
    wtrans_kernel<<<dim3(HDIM / 32, DDIM / 32, NEXP), 256, 0, stream>>>(w1, w1t, DDIM, HDIM);
    wtrans_kernel<<<dim3(DDIM / 32, HDIM / 32, NEXP), 256, 0, stream>>>(w2, w2t, HDIM, DDIM);

    for (int h0 = 0; h0 < HDIM; h0 += hlen) {
        gemm1_kernel<<<dim3(MAXTILE, hlen / GBN), 512, 0, stream>>>(
            xbf, w1t, b1, offs, tile_e, tile_m0, list_tok, hbuf, h0, hlen);
        gemm2_kernel<<<dim3(MAXTILE, DDIM / GBN), 512, 0, stream>>>(
            hbuf, w2t, b2, offs, tile_e, tile_m0, list_tok, list_w, ybuf, out, h0, hlen, mode);
    }
    if (mode == 0)
        combine_kernel<<<T_TOK * 128 / 256, 256, 0, stream>>>(ybuf, pos_tk, tok_w, out);
}